// Round 6
// baseline (194.268 us; speedup 1.0000x reference)
//
#include <hip/hip_runtime.h>
#include <cstdint>
#include <cstddef>

#define N_NODES 50000
#define N_EDGES 800000
#define NE4 (N_EDGES / 4)        // 200000 int4 records
#define DIM 64
#define NREL 8
#define NBLK 782                 // ceil(N_NODES/64)
#define NPAD (NBLK * 64)         // 50048
#define NBUCK 196                // ceil(N_NODES/256): bucket = dst>>8
#define NCHUNK 196               // edge chunks of 4096
#define CHUNK4 1024              // int4 loads per chunk
#define NP (NBUCK * NCHUNK)      // 38416 count-matrix entries
#define NB1 151                  // ceil(NP/256)

typedef unsigned short u16;
typedef unsigned int u32;
typedef float f32x4 __attribute__((ext_vector_type(4)));
typedef short bf16x8 __attribute__((ext_vector_type(8)));

__device__ __forceinline__ u16 f2b(float f) {
  union { float f; u32 u; } c; c.f = f;
  u32 u = c.u;
  return (u16)((u + 0x7fffu + ((u >> 16) & 1u)) >> 16);  // RNE
}
__device__ __forceinline__ float b2f(u16 v) {
  union { u32 u; float f; } c; c.u = ((u32)v) << 16;
  return c.f;
}

// ---- casts -----------------------------------------------------------------
__global__ void k_cast_h(const float* __restrict__ h, u16* __restrict__ hb) {
  size_t i4 = (size_t)blockIdx.x * 256 + threadIdx.x;
  size_t base = i4 * 4;
  if (base >= (size_t)NPAD * DIM) return;
  size_t row = base >> 6;
  u16 o[4];
  if (row < N_NODES) {
    float4 v = *(const float4*)(h + base);
    o[0] = f2b(v.x); o[1] = f2b(v.y); o[2] = f2b(v.z); o[3] = f2b(v.w);
  } else {
    o[0] = o[1] = o[2] = o[3] = 0;
  }
  uint2 s; s.x = (u32)o[0] | ((u32)o[1] << 16); s.y = (u32)o[2] | ((u32)o[3] << 16);
  *(uint2*)(hb + base) = s;
}

// block r: WbT[r][d][k] = W[r][k][d] (bf16); Tb row r = a[r,:D], row 8+r = Wa2[r]
__global__ void k_cast_wt(const float* __restrict__ W, const float* __restrict__ a,
                          u16* __restrict__ WbT, u16* __restrict__ Tb) {
  int r = blockIdx.x;
  for (int idx = threadIdx.x; idx < DIM * DIM; idx += 256) {
    int d = idx >> 6, k = idx & 63;
    WbT[((size_t)r * DIM + d) * DIM + k] = f2b(W[((size_t)r * DIM + k) * DIM + d]);
  }
  if (threadIdx.x < DIM) {
    int d = threadIdx.x;
    const float* Wr = W + (size_t)r * DIM * DIM + (size_t)d * DIM;
    const float* ar = a + (size_t)r * 2 * DIM + DIM;
    float acc = 0.f;
    #pragma unroll
    for (int e = 0; e < DIM; ++e) acc += Wr[e] * ar[e];
    Tb[(8 + r) * DIM + d] = f2b(acc);          // src-side: Wa2[r]
    Tb[r * DIM + d] = f2b(a[r * 2 * DIM + d]); // dst-side: a[r,:D]
  }
}

// tbl[n][t] = hb[n] . Tb[t]   (t: 0..7 dst-side, 8..15 src-side)
__global__ __launch_bounds__(256) void k_tbl(const u16* __restrict__ hb,
                                             const u16* __restrict__ Tb,
                                             float* __restrict__ tbl) {
  const int wv = threadIdx.x >> 6;
  const int lane = threadIdx.x & 63;
  const int l15 = lane & 15;
  const int kg = lane >> 4;
  const int n = blockIdx.x * 64 + wv * 16 + l15;
  const bf16x8* hrow = (const bf16x8*)(hb + (size_t)n * DIM);
  const bf16x8 b0 = hrow[kg];
  const bf16x8 b1 = hrow[4 + kg];
  const bf16x8* trow = (const bf16x8*)(Tb + (size_t)l15 * DIM);
  f32x4 acc = {0.f, 0.f, 0.f, 0.f};
  acc = __builtin_amdgcn_mfma_f32_16x16x32_bf16(trow[kg], b0, acc, 0, 0, 0);
  acc = __builtin_amdgcn_mfma_f32_16x16x32_bf16(trow[4 + kg], b1, acc, 0, 0, 0);
  if (n < N_NODES) *(f32x4*)(tbl + (size_t)n * 16 + kg * 4) = acc;
}

// ---- deterministic two-pass bucket partition -------------------------------
__global__ __launch_bounds__(256) void k_pcount(const int* __restrict__ dst,
                                                int* __restrict__ pcnt) {
  __shared__ int cnt[256];
  const int t = threadIdx.x, c = blockIdx.x;
  cnt[t] = 0;
  __syncthreads();
  const int base4 = c * CHUNK4;
  const int end4 = (base4 + CHUNK4 < NE4) ? base4 + CHUNK4 : NE4;
  for (int i = base4 + t; i < end4; i += 256) {
    int4 d4 = ((const int4*)dst)[i];
    atomicAdd(&cnt[d4.x >> 8], 1);
    atomicAdd(&cnt[d4.y >> 8], 1);
    atomicAdd(&cnt[d4.z >> 8], 1);
    atomicAdd(&cnt[d4.w >> 8], 1);
  }
  __syncthreads();
  if (t < NBUCK) pcnt[t * NCHUNK + c] = cnt[t];
}

__global__ void k_scanA(const int* __restrict__ in, int* __restrict__ out,
                        int* __restrict__ bsum) {
  __shared__ int lds[256];
  int t = threadIdx.x;
  int i = blockIdx.x * 256 + t;
  int v = (i < NP) ? in[i] : 0;
  lds[t] = v;
  __syncthreads();
  #pragma unroll
  for (int off = 1; off < 256; off <<= 1) {
    int tv = (t >= off) ? lds[t - off] : 0;
    __syncthreads();
    lds[t] += tv;
    __syncthreads();
  }
  if (i < NP) out[i] = lds[t] - v;
  if (t == 255) bsum[blockIdx.x] = lds[255];
}

__global__ void k_scanB(const int* __restrict__ bsum, int* __restrict__ boff,
                        int* __restrict__ bbase, int* __restrict__ rowstart) {
  __shared__ int lds[256];
  int t = threadIdx.x;
  int v = (t < NB1) ? bsum[t] : 0;
  lds[t] = v;
  __syncthreads();
  #pragma unroll
  for (int off = 1; off < 256; off <<= 1) {
    int tv = (t >= off) ? lds[t - off] : 0;
    __syncthreads();
    lds[t] += tv;
    __syncthreads();
  }
  if (t < NB1) boff[t] = lds[t] - v;
  if (t == 0) { bbase[NBUCK] = N_EDGES; rowstart[N_NODES] = N_EDGES; }
}

__global__ void k_scanC(int* __restrict__ gbase, const int* __restrict__ boff,
                        int* __restrict__ bbase) {
  int i = blockIdx.x * 256 + threadIdx.x;
  if (i >= NP) return;
  int v = gbase[i] + boff[blockIdx.x];
  gbase[i] = v;
  if (i % NCHUNK == 0) bbase[i / NCHUNK] = v;
}

// pack: bits[15:0]=src, [18:16]=et, [31:24]=dst&255
__global__ __launch_bounds__(256) void k_ppart(const int* __restrict__ src,
                                               const int* __restrict__ dst,
                                               const int* __restrict__ et,
                                               const int* __restrict__ gbase,
                                               u32* __restrict__ tmp) {
  __shared__ int cur[256];
  const int t = threadIdx.x, c = blockIdx.x;
  if (t < NBUCK) cur[t] = gbase[t * NCHUNK + c];
  __syncthreads();
  const int base4 = c * CHUNK4;
  const int end4 = (base4 + CHUNK4 < NE4) ? base4 + CHUNK4 : NE4;
  for (int i = base4 + t; i < end4; i += 256) {
    int4 s4 = ((const int4*)src)[i];
    int4 d4 = ((const int4*)dst)[i];
    int4 t4 = ((const int4*)et)[i];
    int p0 = atomicAdd(&cur[d4.x >> 8], 1);
    int p1 = atomicAdd(&cur[d4.y >> 8], 1);
    int p2 = atomicAdd(&cur[d4.z >> 8], 1);
    int p3 = atomicAdd(&cur[d4.w >> 8], 1);
    tmp[p0] = (u32)s4.x | ((u32)t4.x << 16) | ((u32)(d4.x & 255) << 24);
    tmp[p1] = (u32)s4.y | ((u32)t4.y << 16) | ((u32)(d4.y & 255) << 24);
    tmp[p2] = (u32)s4.z | ((u32)t4.z << 16) | ((u32)(d4.z & 255) << 24);
    tmp[p3] = (u32)s4.w | ((u32)t4.w << 16) | ((u32)(d4.w & 255) << 24);
  }
}

// per bucket: LDS hist+scan -> rowstart + node-grouped epk
__global__ __launch_bounds__(256) void k_local(const u32* __restrict__ tmp,
                                               const int* __restrict__ bbase,
                                               int* __restrict__ rowstart,
                                               int* __restrict__ epk) {
  __shared__ int hist[256];
  __shared__ int excl[256];
  __shared__ int cur[256];
  const int b = blockIdx.x;
  const int t = threadIdx.x;
  const int base = bbase[b];
  const int end = bbase[b + 1];
  hist[t] = 0;
  cur[t] = 0;
  __syncthreads();
  for (int i = base + t; i < end; i += 256) atomicAdd(&hist[tmp[i] >> 24], 1);
  __syncthreads();
  int v = hist[t];
  excl[t] = v;
  __syncthreads();
  #pragma unroll
  for (int off = 1; off < 256; off <<= 1) {
    int tv = (t >= off) ? excl[t - off] : 0;
    __syncthreads();
    excl[t] += tv;
    __syncthreads();
  }
  int myexcl = excl[t] - v;
  excl[t] = myexcl;
  int n = b * 256 + t;
  if (n < N_NODES) rowstart[n] = base + myexcl;
  __syncthreads();
  for (int i = base + t; i < end; i += 256) {
    u32 p = tmp[i];
    int lo = p >> 24;
    int o = atomicAdd(&cur[lo], 1);
    epk[base + excl[lo] + o] = (int)(p & 0x7ffffu);  // (et<<16)|src
  }
}

// ---- gather: wave per dst node; S[n][r][:] = sum_{e in r} w_e * h[sv_e] ----
// lane = dim. Per edge: uniform epk/tbl loads, 128B bf16 h-row gather,
// readfirstlane-uniform relation select into 8 register accumulators.
__global__ __launch_bounds__(256) void k_gather(const u16* __restrict__ hb,
                                                const float* __restrict__ tbl,
                                                const int* __restrict__ rowstart,
                                                const int* __restrict__ epk,
                                                u16* __restrict__ Sb,
                                                float* __restrict__ den) {
  const int node = blockIdx.x * 4 + (threadIdx.x >> 6);
  const int lane = threadIdx.x & 63;
  const int s0 = rowstart[node];
  const int e0 = rowstart[node + 1];
  float s[8] = {0.f, 0.f, 0.f, 0.f, 0.f, 0.f, 0.f, 0.f};
  float dn = 0.f;
  const float* tdst = tbl + (size_t)node * 16;
  for (int j0 = s0; j0 < e0; j0 += 16) {
    #pragma unroll
    for (int j = 0; j < 16; ++j) {
      const int idx = j0 + j;
      const bool valid = idx < e0;
      const int pj = epk[idx];            // uniform addr -> broadcast load
      const int svj = pj & 0xffff;
      const int rvj = (pj >> 16) & 7;
      float lg = tdst[rvj] + tbl[(size_t)svj * 16 + 8 + rvj];
      lg = lg > 0.f ? lg : 0.2f * lg;
      const float wj = valid ? __expf(lg) : 0.f;
      const float hv = b2f(hb[(size_t)svj * DIM + lane]);
      dn += wj;
      const int rs = __builtin_amdgcn_readfirstlane(rvj);
      #pragma unroll
      for (int r = 0; r < 8; ++r)
        if (rs == r) s[r] += wj * hv;
    }
  }
  // pack bf16: even lane stores (dim, dim+1) as u32
  #pragma unroll
  for (int r = 0; r < 8; ++r) {
    const float ps = __shfl_xor(s[r], 1, 64);
    if (!(lane & 1)) {
      u32 word = (u32)f2b(s[r]) | ((u32)f2b(ps) << 16);
      *(u32*)(Sb + (size_t)node * 512 + r * 64 + lane) = word;
    }
  }
  if (lane == 0) den[node] = dn;
}

// ---- red = Sflat[N,512] @ Wflat[512,64] + residual epilogue (MFMA) ---------
// window w (0..15): relation r=w>>1, K-offset (w&1)*32; A row d = WbT[r][d][.]
__global__ __launch_bounds__(256) void k_red(const u16* __restrict__ Sb,
                                             const u16* __restrict__ WbT,
                                             const float* __restrict__ den,
                                             const float* __restrict__ h,
                                             const float* __restrict__ dmask,
                                             float* __restrict__ out) {
  const int wv = threadIdx.x >> 6;
  const int lane = threadIdx.x & 63;
  const int l15 = lane & 15;
  const int kg = lane >> 4;
  const int n = blockIdx.x * 64 + wv * 16 + l15;
  const u16* srow = Sb + (size_t)n * 512;
  f32x4 acc[4];
  #pragma unroll
  for (int dt = 0; dt < 4; ++dt) acc[dt] = (f32x4){0.f, 0.f, 0.f, 0.f};
  #pragma unroll
  for (int w = 0; w < 16; ++w) {
    const bf16x8 bfrag = *(const bf16x8*)(srow + w * 32 + kg * 8);
    const int r = w >> 1;
    const int koff = (w & 1) * 32 + kg * 8;
    #pragma unroll
    for (int dt = 0; dt < 4; ++dt) {
      const bf16x8 afrag =
          *(const bf16x8*)(WbT + ((size_t)r * DIM + dt * 16 + l15) * DIM + koff);
      acc[dt] = __builtin_amdgcn_mfma_f32_16x16x32_bf16(afrag, bfrag, acc[dt], 0, 0, 0);
    }
  }
  if (n < N_NODES) {
    const float inv = 1.f / (den[n] + 1e-9f);
    #pragma unroll
    for (int dt = 0; dt < 4; ++dt) {
      const int d = dt * 16 + kg * 4;
      const float4 hv = *(const float4*)(h + (size_t)n * DIM + d);
      const float4 dm = *(const float4*)(dmask + d);
      float4 o;
      o.x = hv.x + acc[dt][0] * inv * dm.x;
      o.y = hv.y + acc[dt][1] * inv * dm.y;
      o.z = hv.z + acc[dt][2] * inv * dm.z;
      o.w = hv.w + acc[dt][3] * inv * dm.w;
      *(float4*)(out + (size_t)n * DIM + d) = o;
    }
  }
}

extern "C" void kernel_launch(void* const* d_in, const int* in_sizes, int n_in,
                              void* d_out, int out_size, void* d_ws, size_t ws_size,
                              hipStream_t stream) {
  const float* h = (const float*)d_in[0];
  const float* W = (const float*)d_in[1];
  const float* a = (const float*)d_in[2];
  const float* dmask = (const float*)d_in[3];
  const int* src = (const int*)d_in[4];
  const int* dst = (const int*)d_in[5];
  const int* et = (const int*)d_in[6];
  float* out = (float*)d_out;

  char* ws = (char*)d_ws;
  size_t off = 0;
  auto alloc = [&](size_t bytes) {
    void* p = ws + off;
    off += (bytes + 255) & ~(size_t)255;
    return p;
  };
  u16* Sb = (u16*)alloc((size_t)NPAD * 512 * 2);               // 51.2 MB
  u16* hb = (u16*)alloc((size_t)NPAD * DIM * 2);               // 6.4 MB
  u16* WbT = (u16*)alloc((size_t)NREL * DIM * DIM * 2);
  u16* Tb = (u16*)alloc(16 * DIM * 2);
  float* tbl = (float*)alloc((size_t)N_NODES * 16 * 4);        // 3.2 MB
  float* den = (float*)alloc((size_t)NPAD * 4);
  int* rowstart = (int*)alloc((N_NODES + 1) * 4);
  int* pcnt = (int*)alloc(NP * 4);
  int* gbase = (int*)alloc(NP * 4);
  int* bsum = (int*)alloc(NB1 * 4);
  int* boff = (int*)alloc(NB1 * 4);
  int* bbase = (int*)alloc((NBUCK + 1) * 4);
  u32* tmp = (u32*)alloc((size_t)N_EDGES * 4);                 // 3.2 MB
  int* epk = (int*)alloc((size_t)(N_EDGES + 64) * 4);          // +slack for tail reads
  (void)off; (void)ws_size;

  k_cast_h<<<(NPAD * DIM / 4 + 255) / 256, 256, 0, stream>>>(h, hb);
  k_cast_wt<<<NREL, 256, 0, stream>>>(W, a, WbT, Tb);
  k_tbl<<<NBLK, 256, 0, stream>>>(hb, Tb, tbl);
  k_pcount<<<NCHUNK, 256, 0, stream>>>(dst, pcnt);
  k_scanA<<<NB1, 256, 0, stream>>>(pcnt, gbase, bsum);
  k_scanB<<<1, 256, 0, stream>>>(bsum, boff, bbase, rowstart);
  k_scanC<<<NB1, 256, 0, stream>>>(gbase, boff, bbase);
  k_ppart<<<NCHUNK, 256, 0, stream>>>(src, dst, et, gbase, tmp);
  k_local<<<NBUCK, 256, 0, stream>>>(tmp, bbase, rowstart, epk);
  k_gather<<<N_NODES / 4, 256, 0, stream>>>(hb, tbl, rowstart, epk, Sb, den);
  k_red<<<NBLK, 256, 0, stream>>>(Sb, WbT, den, h, dmask, out);
}

// Round 7
// 186.353 us; speedup vs baseline: 1.0425x; 1.0425x over previous
//
#include <hip/hip_runtime.h>
#include <cstdint>
#include <cstddef>

#define N_NODES 50000
#define N_EDGES 800000
#define NE4 (N_EDGES / 4)        // 200000 int4 records
#define DIM 64
#define NREL 8
#define NBLK 782                 // ceil(N_NODES/64)
#define NPAD (NBLK * 64)         // 50048
#define NBUCK 196                // ceil(N_NODES/256): bucket = dst>>8
#define NCHUNK 196               // edge chunks of 4096
#define CHUNK4 1024              // int4 loads per chunk
#define NP (NBUCK * NCHUNK)      // 38416 count-matrix entries
#define SCAN_PT 151              // ceil(NP/256) entries per thread in 1-block scan

typedef unsigned short u16;
typedef unsigned int u32;
typedef float f32x4 __attribute__((ext_vector_type(4)));
typedef short bf16x8 __attribute__((ext_vector_type(8)));

__device__ __forceinline__ u16 f2b(float f) {
  union { float f; u32 u; } c; c.f = f;
  u32 u = c.u;
  return (u16)((u + 0x7fffu + ((u >> 16) & 1u)) >> 16);  // RNE
}
__device__ __forceinline__ float b2f(u16 v) {
  union { u32 u; float f; } c; c.u = ((u32)v) << 16;
  return c.f;
}

// ==== P1: blocks 0..195 = per-chunk bucket histogram; 196..203 = W/a prep ===
__global__ __launch_bounds__(256) void k_phase1(const int* __restrict__ dst,
                                                const float* __restrict__ W,
                                                const float* __restrict__ a,
                                                int* __restrict__ pcnt,
                                                u16* __restrict__ WbT,
                                                u16* __restrict__ Tb) {
  __shared__ int cnt[256];
  const int t = threadIdx.x;
  if (blockIdx.x < NCHUNK) {
    const int c = blockIdx.x;
    cnt[t] = 0;
    __syncthreads();
    const int base4 = c * CHUNK4;
    const int end4 = (base4 + CHUNK4 < NE4) ? base4 + CHUNK4 : NE4;
    for (int i = base4 + t; i < end4; i += 256) {
      int4 d4 = ((const int4*)dst)[i];
      atomicAdd(&cnt[d4.x >> 8], 1);
      atomicAdd(&cnt[d4.y >> 8], 1);
      atomicAdd(&cnt[d4.z >> 8], 1);
      atomicAdd(&cnt[d4.w >> 8], 1);
    }
    __syncthreads();
    if (t < NBUCK) pcnt[t * NCHUNK + c] = cnt[t];
  } else {
    const int r = blockIdx.x - NCHUNK;
    for (int idx = t; idx < DIM * DIM; idx += 256) {
      int d = idx >> 6, k = idx & 63;
      WbT[((size_t)r * DIM + d) * DIM + k] = f2b(W[((size_t)r * DIM + k) * DIM + d]);
    }
    if (t < DIM) {
      int d = t;
      const float* Wr = W + (size_t)r * DIM * DIM + (size_t)d * DIM;
      const float* ar = a + (size_t)r * 2 * DIM + DIM;
      float acc = 0.f;
      #pragma unroll
      for (int e = 0; e < DIM; ++e) acc += Wr[e] * ar[e];
      Tb[(8 + r) * DIM + d] = f2b(acc);          // src-side: Wa2[r]
      Tb[r * DIM + d] = f2b(a[r * 2 * DIM + d]); // dst-side: a[r,:D]
    }
  }
}

// ==== P2: blocks 0..781 = fused h-cast + logit-table MFMA; block 782 = scan =
__global__ __launch_bounds__(256) void k_phase2(const float* __restrict__ h,
                                                const u16* __restrict__ Tb,
                                                const int* __restrict__ pcnt,
                                                u16* __restrict__ hb,
                                                float* __restrict__ tbl,
                                                int* __restrict__ gbase,
                                                int* __restrict__ bbase,
                                                int* __restrict__ rowstart) {
  __shared__ int lds[256];
  const int t = threadIdx.x;
  if (blockIdx.x < NBLK) {
    const int wv = t >> 6;
    const int lane = t & 63;
    const int l15 = lane & 15;
    const int kg = lane >> 4;
    const int n = blockIdx.x * 64 + wv * 16 + l15;
    const int nn = (n < N_NODES) ? n : N_NODES - 1;  // clamp reads; mask stores
    const float4* hr = (const float4*)(h + (size_t)nn * DIM);
    const float4 a0 = hr[kg * 2], a1 = hr[kg * 2 + 1];
    const float4 a2 = hr[8 + kg * 2], a3 = hr[8 + kg * 2 + 1];
    union { bf16x8 v; u32 w[4]; } b0, b1;
    b0.w[0] = (u32)f2b(a0.x) | ((u32)f2b(a0.y) << 16);
    b0.w[1] = (u32)f2b(a0.z) | ((u32)f2b(a0.w) << 16);
    b0.w[2] = (u32)f2b(a1.x) | ((u32)f2b(a1.y) << 16);
    b0.w[3] = (u32)f2b(a1.z) | ((u32)f2b(a1.w) << 16);
    b1.w[0] = (u32)f2b(a2.x) | ((u32)f2b(a2.y) << 16);
    b1.w[1] = (u32)f2b(a2.z) | ((u32)f2b(a2.w) << 16);
    b1.w[2] = (u32)f2b(a3.x) | ((u32)f2b(a3.y) << 16);
    b1.w[3] = (u32)f2b(a3.z) | ((u32)f2b(a3.w) << 16);
    const bool ok = (n < N_NODES);
    if (ok) {
      *(bf16x8*)(hb + (size_t)n * DIM + kg * 8) = b0.v;
      *(bf16x8*)(hb + (size_t)n * DIM + 32 + kg * 8) = b1.v;
    }
    const bf16x8* trow = (const bf16x8*)(Tb + (size_t)l15 * DIM);
    f32x4 acc = {0.f, 0.f, 0.f, 0.f};
    acc = __builtin_amdgcn_mfma_f32_16x16x32_bf16(trow[kg], b0.v, acc, 0, 0, 0);
    acc = __builtin_amdgcn_mfma_f32_16x16x32_bf16(trow[4 + kg], b1.v, acc, 0, 0, 0);
    if (ok) *(f32x4*)(tbl + (size_t)n * 16 + kg * 4) = acc;
  } else {
    // single-block exclusive scan of pcnt[NP] -> gbase, bbase
    const int base = t * SCAN_PT;
    int s = 0;
    for (int i = 0; i < SCAN_PT; ++i) {
      int idx = base + i;
      if (idx < NP) s += pcnt[idx];
    }
    lds[t] = s;
    __syncthreads();
    #pragma unroll
    for (int off = 1; off < 256; off <<= 1) {
      int tv = (t >= off) ? lds[t - off] : 0;
      __syncthreads();
      lds[t] += tv;
      __syncthreads();
    }
    int run = lds[t] - s;  // exclusive prefix
    for (int i = 0; i < SCAN_PT; ++i) {
      int idx = base + i;
      if (idx < NP) {
        gbase[idx] = run;
        if (idx % NCHUNK == 0) bbase[idx / NCHUNK] = run;
        run += pcnt[idx];
      }
    }
    if (t == 0) { bbase[NBUCK] = N_EDGES; rowstart[N_NODES] = N_EDGES; }
  }
}

// ==== P3: blocks 0..195 = partition pass 2; 196..977 = hW MFMA GEMM =========
// pack: bits[15:0]=src, [18:16]=et, [31:24]=dst&255
__global__ __launch_bounds__(256) void k_phase3(const int* __restrict__ src,
                                                const int* __restrict__ dst,
                                                const int* __restrict__ et,
                                                const int* __restrict__ gbase,
                                                u32* __restrict__ tmp,
                                                const u16* __restrict__ hb,
                                                const u16* __restrict__ WbT,
                                                u16* __restrict__ hW) {
  __shared__ int cur[256];
  const int t = threadIdx.x;
  if (blockIdx.x < NCHUNK) {
    const int c = blockIdx.x;
    if (t < NBUCK) cur[t] = gbase[t * NCHUNK + c];
    __syncthreads();
    const int base4 = c * CHUNK4;
    const int end4 = (base4 + CHUNK4 < NE4) ? base4 + CHUNK4 : NE4;
    for (int i = base4 + t; i < end4; i += 256) {
      int4 s4 = ((const int4*)src)[i];
      int4 d4 = ((const int4*)dst)[i];
      int4 t4 = ((const int4*)et)[i];
      int p0 = atomicAdd(&cur[d4.x >> 8], 1);
      int p1 = atomicAdd(&cur[d4.y >> 8], 1);
      int p2 = atomicAdd(&cur[d4.z >> 8], 1);
      int p3 = atomicAdd(&cur[d4.w >> 8], 1);
      tmp[p0] = (u32)s4.x | ((u32)t4.x << 16) | ((u32)(d4.x & 255) << 24);
      tmp[p1] = (u32)s4.y | ((u32)t4.y << 16) | ((u32)(d4.y & 255) << 24);
      tmp[p2] = (u32)s4.z | ((u32)t4.z << 16) | ((u32)(d4.z & 255) << 24);
      tmp[p3] = (u32)s4.w | ((u32)t4.w << 16) | ((u32)(d4.w & 255) << 24);
    }
  } else {
    const int bid = blockIdx.x - NCHUNK;
    const int wv = t >> 6;
    const int lane = t & 63;
    const int l15 = lane & 15;
    const int kg = lane >> 4;
    const int n = bid * 64 + wv * 16 + l15;
    const bf16x8* hrow = (const bf16x8*)(hb + (size_t)n * DIM);
    const bf16x8 b0 = hrow[kg];
    const bf16x8 b1 = hrow[4 + kg];
    const bool ok = (n < N_NODES);
    #pragma unroll
    for (int r = 0; r < NREL; ++r) {
      #pragma unroll
      for (int dt = 0; dt < 4; ++dt) {
        const int d = dt * 16 + l15;
        const bf16x8* wrow = (const bf16x8*)(WbT + ((size_t)r * DIM + d) * DIM);
        f32x4 acc = {0.f, 0.f, 0.f, 0.f};
        acc = __builtin_amdgcn_mfma_f32_16x16x32_bf16(wrow[kg], b0, acc, 0, 0, 0);
        acc = __builtin_amdgcn_mfma_f32_16x16x32_bf16(wrow[4 + kg], b1, acc, 0, 0, 0);
        if (ok) {
          uint2 s;
          s.x = (u32)f2b(acc[0]) | ((u32)f2b(acc[1]) << 16);
          s.y = (u32)f2b(acc[2]) | ((u32)f2b(acc[3]) << 16);
          *(uint2*)(hW + ((size_t)r * N_NODES + n) * DIM + dt * 16 + kg * 4) = s;
        }
      }
    }
  }
}

// ==== P4: per bucket LDS hist+scan -> rowstart + node-grouped epk ===========
__global__ __launch_bounds__(256) void k_local(const u32* __restrict__ tmp,
                                               const int* __restrict__ bbase,
                                               int* __restrict__ rowstart,
                                               int* __restrict__ epk) {
  __shared__ int hist[256];
  __shared__ int excl[256];
  __shared__ int cur[256];
  const int b = blockIdx.x;
  const int t = threadIdx.x;
  const int base = bbase[b];
  const int end = bbase[b + 1];
  hist[t] = 0;
  cur[t] = 0;
  __syncthreads();
  for (int i = base + t; i < end; i += 256) atomicAdd(&hist[tmp[i] >> 24], 1);
  __syncthreads();
  int v = hist[t];
  excl[t] = v;
  __syncthreads();
  #pragma unroll
  for (int off = 1; off < 256; off <<= 1) {
    int tv = (t >= off) ? excl[t - off] : 0;
    __syncthreads();
    excl[t] += tv;
    __syncthreads();
  }
  int myexcl = excl[t] - v;
  excl[t] = myexcl;
  int n = b * 256 + t;
  if (n < N_NODES) rowstart[n] = base + myexcl;
  __syncthreads();
  for (int i = base + t; i < end; i += 256) {
    u32 p = tmp[i];
    int lo = p >> 24;
    int o = atomicAdd(&cur[lo], 1);
    epk[base + excl[lo] + o] = (int)(p & 0x7ffffu);  // (et<<16)|src
  }
}

// ==== P5: fused softmax+reduce: wave/node, 16 edge slots x 4 lanes ==========
__global__ void k_fused(const float* __restrict__ h, const u16* __restrict__ hW,
                        const float* __restrict__ tbl,
                        const int* __restrict__ rowstart, const int* __restrict__ epk,
                        const float* __restrict__ dmask, float* __restrict__ out) {
  const int node = blockIdx.x * 4 + (threadIdx.x >> 6);
  const int lane = threadIdx.x & 63;
  const int g = lane >> 2;   // edge slot 0..15
  const int l = lane & 3;    // 32B quarter of the 128B row
  const int s = rowstart[node];
  const int e = rowstart[node + 1];
  float acc[16];
  #pragma unroll
  for (int i = 0; i < 16; ++i) acc[i] = 0.f;
  float den = 0.f;
  for (int j = s; j < e; j += 16) {
    const int idx = j + g;
    const bool valid = idx < e;
    const int p = valid ? epk[idx] : 0;
    const int sv = p & 0xffff;
    const int rv = (p >> 16) & 7;
    float lg = tbl[(size_t)node * 16 + rv] + tbl[(size_t)sv * 16 + 8 + rv];
    lg = lg > 0.f ? lg : 0.2f * lg;
    const float w = valid ? __expf(lg) : 0.f;
    den += w;
    uint4 q0 = {0u, 0u, 0u, 0u}, q1 = {0u, 0u, 0u, 0u};
    if (valid) {
      const u16* row = hW + ((size_t)rv * N_NODES + sv) * DIM + l * 16;
      q0 = *(const uint4*)row;
      q1 = *(const uint4*)(row + 8);
    }
    const u32 qa[8] = {q0.x, q0.y, q0.z, q0.w, q1.x, q1.y, q1.z, q1.w};
    #pragma unroll
    for (int c = 0; c < 8; ++c) {
      acc[2 * c]     += w * b2f((u16)(qa[c] & 0xffff));
      acc[2 * c + 1] += w * b2f((u16)(qa[c] >> 16));
    }
  }
  #pragma unroll
  for (int m = 4; m <= 32; m <<= 1) {
    den += __shfl_xor(den, m, 64);
    #pragma unroll
    for (int i = 0; i < 16; ++i) acc[i] += __shfl_xor(acc[i], m, 64);
  }
  if (lane < 4) {
    const float inv = 1.f / (den + 1e-9f);
    #pragma unroll
    for (int c = 0; c < 4; ++c) {
      const float4 hv = *(const float4*)(h + (size_t)node * DIM + l * 16 + c * 4);
      const float4 dm = *(const float4*)(dmask + l * 16 + c * 4);
      float4 o;
      o.x = hv.x + acc[c * 4 + 0] * inv * dm.x;
      o.y = hv.y + acc[c * 4 + 1] * inv * dm.y;
      o.z = hv.z + acc[c * 4 + 2] * inv * dm.z;
      o.w = hv.w + acc[c * 4 + 3] * inv * dm.w;
      *(float4*)(out + (size_t)node * DIM + l * 16 + c * 4) = o;
    }
  }
}

extern "C" void kernel_launch(void* const* d_in, const int* in_sizes, int n_in,
                              void* d_out, int out_size, void* d_ws, size_t ws_size,
                              hipStream_t stream) {
  const float* h = (const float*)d_in[0];
  const float* W = (const float*)d_in[1];
  const float* a = (const float*)d_in[2];
  const float* dmask = (const float*)d_in[3];
  const int* src = (const int*)d_in[4];
  const int* dst = (const int*)d_in[5];
  const int* et = (const int*)d_in[6];
  float* out = (float*)d_out;

  char* ws = (char*)d_ws;
  size_t off = 0;
  auto alloc = [&](size_t bytes) {
    void* p = ws + off;
    off += (bytes + 255) & ~(size_t)255;
    return p;
  };
  u16* hWbuf = (u16*)alloc((size_t)NREL * N_NODES * DIM * 2);  // 51.2 MB
  u16* hb = (u16*)alloc((size_t)NPAD * DIM * 2);               // 6.4 MB
  u16* WbT = (u16*)alloc((size_t)NREL * DIM * DIM * 2);
  u16* Tb = (u16*)alloc(16 * DIM * 2);
  float* tbl = (float*)alloc((size_t)N_NODES * 16 * 4);        // 3.2 MB
  int* rowstart = (int*)alloc((N_NODES + 1) * 4);
  int* pcnt = (int*)alloc(NP * 4);
  int* gbase = (int*)alloc(NP * 4);
  int* bbase = (int*)alloc((NBUCK + 1) * 4);
  u32* tmp = (u32*)alloc((size_t)N_EDGES * 4);                 // 3.2 MB
  int* epk = (int*)alloc((size_t)(N_EDGES + 64) * 4);
  (void)off; (void)ws_size;

  k_phase1<<<NCHUNK + NREL, 256, 0, stream>>>(dst, W, a, pcnt, WbT, Tb);
  k_phase2<<<NBLK + 1, 256, 0, stream>>>(h, Tb, pcnt, hb, tbl, gbase, bbase, rowstart);
  k_phase3<<<NCHUNK + NBLK, 256, 0, stream>>>(src, dst, et, gbase, tmp, hb, WbT, hWbuf);
  k_local<<<NBUCK, 256, 0, stream>>>(tmp, bbase, rowstart, epk);
  k_fused<<<N_NODES / 4, 256, 0, stream>>>(h, hWbuf, tbl, rowstart, epk, dmask, out);
}

// Round 8
// 107.964 us; speedup vs baseline: 1.7994x; 1.7261x over previous
//
#include <hip/hip_runtime.h>
#include <cstdint>
#include <cstddef>

#define N_NODES 50000
#define N_EDGES 800000
#define NE4 (N_EDGES / 4)        // 200000 int4 records
#define DIM 64
#define NREL 8
#define NBLK 782                 // ceil(N_NODES/64)
#define NPAD (NBLK * 64)         // 50048
#define NBUCK 196                // ceil(N_NODES/256): bucket = dst>>8
#define NCHUNK 196               // edge chunks of 4096
#define CHUNK4 1024              // int4 loads per chunk
#define NP (NBUCK * NCHUNK)      // 38416 count-matrix entries
#define NSCAN 151                // ceil(NP/256) scanA blocks

typedef unsigned short u16;
typedef unsigned int u32;
typedef float f32x4 __attribute__((ext_vector_type(4)));
typedef short bf16x8 __attribute__((ext_vector_type(8)));

__device__ __forceinline__ u16 f2b(float f) {
  union { float f; u32 u; } c; c.f = f;
  u32 u = c.u;
  return (u16)((u + 0x7fffu + ((u >> 16) & 1u)) >> 16);  // RNE
}
__device__ __forceinline__ float b2f(u16 v) {
  union { u32 u; float f; } c; c.u = ((u32)v) << 16;
  return c.f;
}

// ==== P1: blocks 0..195 = per-chunk bucket histogram; 196..203 = W/a prep ===
__global__ __launch_bounds__(256) void k_phase1(const int* __restrict__ dst,
                                                const float* __restrict__ W,
                                                const float* __restrict__ a,
                                                int* __restrict__ pcnt,
                                                u16* __restrict__ WbT,
                                                u16* __restrict__ Tb) {
  __shared__ int cnt[256];
  const int t = threadIdx.x;
  if (blockIdx.x < NCHUNK) {
    const int c = blockIdx.x;
    cnt[t] = 0;
    __syncthreads();
    const int base4 = c * CHUNK4;
    const int end4 = (base4 + CHUNK4 < NE4) ? base4 + CHUNK4 : NE4;
    for (int i = base4 + t; i < end4; i += 256) {
      int4 d4 = ((const int4*)dst)[i];
      atomicAdd(&cnt[d4.x >> 8], 1);
      atomicAdd(&cnt[d4.y >> 8], 1);
      atomicAdd(&cnt[d4.z >> 8], 1);
      atomicAdd(&cnt[d4.w >> 8], 1);
    }
    __syncthreads();
    if (t < NBUCK) pcnt[t * NCHUNK + c] = cnt[t];
  } else {
    const int r = blockIdx.x - NCHUNK;
    for (int idx = t; idx < DIM * DIM; idx += 256) {
      int d = idx >> 6, k = idx & 63;
      WbT[((size_t)r * DIM + d) * DIM + k] = f2b(W[((size_t)r * DIM + k) * DIM + d]);
    }
    if (t < DIM) {
      int d = t;
      const float* Wr = W + (size_t)r * DIM * DIM + (size_t)d * DIM;
      const float* ar = a + (size_t)r * 2 * DIM + DIM;
      float acc = 0.f;
      #pragma unroll
      for (int e = 0; e < DIM; ++e) acc += Wr[e] * ar[e];
      Tb[(8 + r) * DIM + d] = f2b(acc);          // src-side: Wa2[r]
      Tb[r * DIM + d] = f2b(a[r * 2 * DIM + d]); // dst-side: a[r,:D]
    }
  }
}

// ==== P2: blocks 0..781 = fused h-cast + logit-table MFMA;
//          blocks 782..932 = scanA (block-local scan of pcnt -> gbase, bsum) =
__global__ __launch_bounds__(256) void k_phase2(const float* __restrict__ h,
                                                const u16* __restrict__ Tb,
                                                const int* __restrict__ pcnt,
                                                u16* __restrict__ hb,
                                                float* __restrict__ tbl,
                                                int* __restrict__ gbase,
                                                int* __restrict__ bsum) {
  __shared__ int lds[256];
  const int t = threadIdx.x;
  if (blockIdx.x < NBLK) {
    const int wv = t >> 6;
    const int lane = t & 63;
    const int l15 = lane & 15;
    const int kg = lane >> 4;
    const int n = blockIdx.x * 64 + wv * 16 + l15;
    const int nn = (n < N_NODES) ? n : N_NODES - 1;  // clamp reads; mask stores
    const float4* hr = (const float4*)(h + (size_t)nn * DIM);
    const float4 a0 = hr[kg * 2], a1 = hr[kg * 2 + 1];
    const float4 a2 = hr[8 + kg * 2], a3 = hr[8 + kg * 2 + 1];
    union { bf16x8 v; u32 w[4]; } b0, b1;
    b0.w[0] = (u32)f2b(a0.x) | ((u32)f2b(a0.y) << 16);
    b0.w[1] = (u32)f2b(a0.z) | ((u32)f2b(a0.w) << 16);
    b0.w[2] = (u32)f2b(a1.x) | ((u32)f2b(a1.y) << 16);
    b0.w[3] = (u32)f2b(a1.z) | ((u32)f2b(a1.w) << 16);
    b1.w[0] = (u32)f2b(a2.x) | ((u32)f2b(a2.y) << 16);
    b1.w[1] = (u32)f2b(a2.z) | ((u32)f2b(a2.w) << 16);
    b1.w[2] = (u32)f2b(a3.x) | ((u32)f2b(a3.y) << 16);
    b1.w[3] = (u32)f2b(a3.z) | ((u32)f2b(a3.w) << 16);
    const bool ok = (n < N_NODES);
    if (ok) {
      *(bf16x8*)(hb + (size_t)n * DIM + kg * 8) = b0.v;
      *(bf16x8*)(hb + (size_t)n * DIM + 32 + kg * 8) = b1.v;
    }
    const bf16x8* trow = (const bf16x8*)(Tb + (size_t)l15 * DIM);
    f32x4 acc = {0.f, 0.f, 0.f, 0.f};
    acc = __builtin_amdgcn_mfma_f32_16x16x32_bf16(trow[kg], b0.v, acc, 0, 0, 0);
    acc = __builtin_amdgcn_mfma_f32_16x16x32_bf16(trow[4 + kg], b1.v, acc, 0, 0, 0);
    if (ok) *(f32x4*)(tbl + (size_t)n * 16 + kg * 4) = acc;
  } else {
    const int sid = blockIdx.x - NBLK;      // 0..150
    const int i = sid * 256 + t;
    const int v = (i < NP) ? pcnt[i] : 0;
    lds[t] = v;
    __syncthreads();
    #pragma unroll
    for (int off = 1; off < 256; off <<= 1) {
      int tv = (t >= off) ? lds[t - off] : 0;
      __syncthreads();
      lds[t] += tv;
      __syncthreads();
    }
    if (i < NP) gbase[i] = lds[t] - v;      // block-local exclusive
    if (t == 255) bsum[sid] = lds[255];
  }
}

// ==== P3: single tiny block: scan bsum[151] -> boff ========================
__global__ void k_scanB(const int* __restrict__ bsum, int* __restrict__ boff,
                        int* __restrict__ rowstart) {
  __shared__ int lds[256];
  int t = threadIdx.x;
  int v = (t < NSCAN) ? bsum[t] : 0;
  lds[t] = v;
  __syncthreads();
  #pragma unroll
  for (int off = 1; off < 256; off <<= 1) {
    int tv = (t >= off) ? lds[t - off] : 0;
    __syncthreads();
    lds[t] += tv;
    __syncthreads();
  }
  if (t < NSCAN) boff[t] = lds[t] - v;
  if (t == 0) rowstart[N_NODES] = N_EDGES;
}

// ==== P4: blocks 0..195 = partition pass 2; 196..977 = hW MFMA GEMM =========
// global base of entry i = gbase[i] + boff[i>>8]
// pack: bits[15:0]=src, [18:16]=et, [31:24]=dst&255
__global__ __launch_bounds__(256) void k_phase4(const int* __restrict__ src,
                                                const int* __restrict__ dst,
                                                const int* __restrict__ et,
                                                const int* __restrict__ gbase,
                                                const int* __restrict__ boff,
                                                u32* __restrict__ tmp,
                                                const u16* __restrict__ hb,
                                                const u16* __restrict__ WbT,
                                                u16* __restrict__ hW) {
  __shared__ int cur[256];
  const int t = threadIdx.x;
  if (blockIdx.x < NCHUNK) {
    const int c = blockIdx.x;
    if (t < NBUCK) {
      const int idx = t * NCHUNK + c;
      cur[t] = gbase[idx] + boff[idx >> 8];
    }
    __syncthreads();
    const int base4 = c * CHUNK4;
    const int end4 = (base4 + CHUNK4 < NE4) ? base4 + CHUNK4 : NE4;
    for (int i = base4 + t; i < end4; i += 256) {
      int4 s4 = ((const int4*)src)[i];
      int4 d4 = ((const int4*)dst)[i];
      int4 t4 = ((const int4*)et)[i];
      int p0 = atomicAdd(&cur[d4.x >> 8], 1);
      int p1 = atomicAdd(&cur[d4.y >> 8], 1);
      int p2 = atomicAdd(&cur[d4.z >> 8], 1);
      int p3 = atomicAdd(&cur[d4.w >> 8], 1);
      tmp[p0] = (u32)s4.x | ((u32)t4.x << 16) | ((u32)(d4.x & 255) << 24);
      tmp[p1] = (u32)s4.y | ((u32)t4.y << 16) | ((u32)(d4.y & 255) << 24);
      tmp[p2] = (u32)s4.z | ((u32)t4.z << 16) | ((u32)(d4.z & 255) << 24);
      tmp[p3] = (u32)s4.w | ((u32)t4.w << 16) | ((u32)(d4.w & 255) << 24);
    }
  } else {
    const int bid = blockIdx.x - NCHUNK;
    const int wv = t >> 6;
    const int lane = t & 63;
    const int l15 = lane & 15;
    const int kg = lane >> 4;
    const int n = bid * 64 + wv * 16 + l15;
    const bf16x8* hrow = (const bf16x8*)(hb + (size_t)n * DIM);
    const bf16x8 b0 = hrow[kg];
    const bf16x8 b1 = hrow[4 + kg];
    const bool ok = (n < N_NODES);
    #pragma unroll
    for (int r = 0; r < NREL; ++r) {
      #pragma unroll
      for (int dt = 0; dt < 4; ++dt) {
        const int d = dt * 16 + l15;
        const bf16x8* wrow = (const bf16x8*)(WbT + ((size_t)r * DIM + d) * DIM);
        f32x4 acc = {0.f, 0.f, 0.f, 0.f};
        acc = __builtin_amdgcn_mfma_f32_16x16x32_bf16(wrow[kg], b0, acc, 0, 0, 0);
        acc = __builtin_amdgcn_mfma_f32_16x16x32_bf16(wrow[4 + kg], b1, acc, 0, 0, 0);
        if (ok) {
          uint2 s;
          s.x = (u32)f2b(acc[0]) | ((u32)f2b(acc[1]) << 16);
          s.y = (u32)f2b(acc[2]) | ((u32)f2b(acc[3]) << 16);
          *(uint2*)(hW + ((size_t)r * N_NODES + n) * DIM + dt * 16 + kg * 4) = s;
        }
      }
    }
  }
}

// ==== P5: per bucket LDS hist+scan -> rowstart + node-grouped epk ===========
__global__ __launch_bounds__(256) void k_local(const u32* __restrict__ tmp,
                                               const int* __restrict__ gbase,
                                               const int* __restrict__ boff,
                                               int* __restrict__ rowstart,
                                               int* __restrict__ epk) {
  __shared__ int hist[256];
  __shared__ int excl[256];
  __shared__ int cur[256];
  const int b = blockIdx.x;
  const int t = threadIdx.x;
  const int i0 = b * NCHUNK;
  const int base = gbase[i0] + boff[i0 >> 8];
  const int end = (b == NBUCK - 1)
                      ? N_EDGES
                      : (gbase[i0 + NCHUNK] + boff[(i0 + NCHUNK) >> 8]);
  hist[t] = 0;
  cur[t] = 0;
  __syncthreads();
  for (int i = base + t; i < end; i += 256) atomicAdd(&hist[tmp[i] >> 24], 1);
  __syncthreads();
  int v = hist[t];
  excl[t] = v;
  __syncthreads();
  #pragma unroll
  for (int off = 1; off < 256; off <<= 1) {
    int tv = (t >= off) ? excl[t - off] : 0;
    __syncthreads();
    excl[t] += tv;
    __syncthreads();
  }
  int myexcl = excl[t] - v;
  excl[t] = myexcl;
  int n = b * 256 + t;
  if (n < N_NODES) rowstart[n] = base + myexcl;
  __syncthreads();
  for (int i = base + t; i < end; i += 256) {
    u32 p = tmp[i];
    int lo = p >> 24;
    int o = atomicAdd(&cur[lo], 1);
    epk[base + excl[lo] + o] = (int)(p & 0x7ffffu);  // (et<<16)|src
  }
}

// ==== P6: fused softmax+reduce: wave/node, 16 edge slots x 4 lanes ==========
__global__ void k_fused(const float* __restrict__ h, const u16* __restrict__ hW,
                        const float* __restrict__ tbl,
                        const int* __restrict__ rowstart, const int* __restrict__ epk,
                        const float* __restrict__ dmask, float* __restrict__ out) {
  const int node = blockIdx.x * 4 + (threadIdx.x >> 6);
  const int lane = threadIdx.x & 63;
  const int g = lane >> 2;   // edge slot 0..15
  const int l = lane & 3;    // 32B quarter of the 128B row
  const int s = rowstart[node];
  const int e = rowstart[node + 1];
  float acc[16];
  #pragma unroll
  for (int i = 0; i < 16; ++i) acc[i] = 0.f;
  float den = 0.f;
  for (int j = s; j < e; j += 16) {
    const int idx = j + g;
    const bool valid = idx < e;
    const int p = valid ? epk[idx] : 0;
    const int sv = p & 0xffff;
    const int rv = (p >> 16) & 7;
    float lg = tbl[(size_t)node * 16 + rv] + tbl[(size_t)sv * 16 + 8 + rv];
    lg = lg > 0.f ? lg : 0.2f * lg;
    const float w = valid ? __expf(lg) : 0.f;
    den += w;
    uint4 q0 = {0u, 0u, 0u, 0u}, q1 = {0u, 0u, 0u, 0u};
    if (valid) {
      const u16* row = hW + ((size_t)rv * N_NODES + sv) * DIM + l * 16;
      q0 = *(const uint4*)row;
      q1 = *(const uint4*)(row + 8);
    }
    const u32 qa[8] = {q0.x, q0.y, q0.z, q0.w, q1.x, q1.y, q1.z, q1.w};
    #pragma unroll
    for (int c = 0; c < 8; ++c) {
      acc[2 * c]     += w * b2f((u16)(qa[c] & 0xffff));
      acc[2 * c + 1] += w * b2f((u16)(qa[c] >> 16));
    }
  }
  #pragma unroll
  for (int m = 4; m <= 32; m <<= 1) {
    den += __shfl_xor(den, m, 64);
    #pragma unroll
    for (int i = 0; i < 16; ++i) acc[i] += __shfl_xor(acc[i], m, 64);
  }
  if (lane < 4) {
    const float inv = 1.f / (den + 1e-9f);
    #pragma unroll
    for (int c = 0; c < 4; ++c) {
      const float4 hv = *(const float4*)(h + (size_t)node * DIM + l * 16 + c * 4);
      const float4 dm = *(const float4*)(dmask + l * 16 + c * 4);
      float4 o;
      o.x = hv.x + acc[c * 4 + 0] * inv * dm.x;
      o.y = hv.y + acc[c * 4 + 1] * inv * dm.y;
      o.z = hv.z + acc[c * 4 + 2] * inv * dm.z;
      o.w = hv.w + acc[c * 4 + 3] * inv * dm.w;
      *(float4*)(out + (size_t)node * DIM + l * 16 + c * 4) = o;
    }
  }
}

extern "C" void kernel_launch(void* const* d_in, const int* in_sizes, int n_in,
                              void* d_out, int out_size, void* d_ws, size_t ws_size,
                              hipStream_t stream) {
  const float* h = (const float*)d_in[0];
  const float* W = (const float*)d_in[1];
  const float* a = (const float*)d_in[2];
  const float* dmask = (const float*)d_in[3];
  const int* src = (const int*)d_in[4];
  const int* dst = (const int*)d_in[5];
  const int* et = (const int*)d_in[6];
  float* out = (float*)d_out;

  char* ws = (char*)d_ws;
  size_t off = 0;
  auto alloc = [&](size_t bytes) {
    void* p = ws + off;
    off += (bytes + 255) & ~(size_t)255;
    return p;
  };
  u16* hWbuf = (u16*)alloc((size_t)NREL * N_NODES * DIM * 2);  // 51.2 MB
  u16* hb = (u16*)alloc((size_t)NPAD * DIM * 2);               // 6.4 MB
  u16* WbT = (u16*)alloc((size_t)NREL * DIM * DIM * 2);
  u16* Tb = (u16*)alloc(16 * DIM * 2);
  float* tbl = (float*)alloc((size_t)N_NODES * 16 * 4);        // 3.2 MB
  int* rowstart = (int*)alloc((N_NODES + 1) * 4);
  int* pcnt = (int*)alloc(NP * 4);
  int* gbase = (int*)alloc(NP * 4);
  int* bsum = (int*)alloc(NSCAN * 4);
  int* boff = (int*)alloc(NSCAN * 4);
  u32* tmp = (u32*)alloc((size_t)N_EDGES * 4);                 // 3.2 MB
  int* epk = (int*)alloc((size_t)(N_EDGES + 64) * 4);
  (void)off; (void)ws_size;

  k_phase1<<<NCHUNK + NREL, 256, 0, stream>>>(dst, W, a, pcnt, WbT, Tb);
  k_phase2<<<NBLK + NSCAN, 256, 0, stream>>>(h, Tb, pcnt, hb, tbl, gbase, bsum);
  k_scanB<<<1, 256, 0, stream>>>(bsum, boff, rowstart);
  k_phase4<<<NCHUNK + NBLK, 256, 0, stream>>>(src, dst, et, gbase, boff, tmp, hb,
                                              WbT, hWbuf);
  k_local<<<NBUCK, 256, 0, stream>>>(tmp, gbase, boff, rowstart, epk);
  k_fused<<<N_NODES / 4, 256, 0, stream>>>(h, hWbuf, tbl, rowstart, epk, dmask, out);
}